// Round 6
// baseline (129.264 us; speedup 1.0000x reference)
//
#include <hip/hip_runtime.h>
#include <hip/hip_bf16.h>
#include <cmath>

#define R_ 64
#define B_ 4096
#define D_ 512
#define C_ 128

typedef __attribute__((ext_vector_type(8))) short bf16x8;
typedef __attribute__((ext_vector_type(4))) float f32x4;

__device__ __forceinline__ unsigned short f2bf(float f) {
  union { float f; unsigned u; } x; x.f = f;
  unsigned r = (x.u + 0x7FFFu + ((x.u >> 16) & 1u)) >> 16;
  return (unsigned short)r;
}

// ---------------- prep: x f32 -> bf16 ----------------
__global__ void prep_x_kernel(const float* __restrict__ x, unsigned short* __restrict__ xw) {
  int i = blockIdx.x * 256 + threadIdx.x;          // float4 index, exact count
  float4 v = reinterpret_cast<const float4*>(x)[i];
  ushort4 o;
  o.x = f2bf(v.x); o.y = f2bf(v.y); o.z = f2bf(v.z); o.w = f2bf(v.w);
  reinterpret_cast<ushort4*>(xw)[i] = o;
}

// ---------------- prep: W[r][d][c] f32 -> W^T[r][c][d] bf16 ----------------
__global__ void prep_w_kernel(const float* __restrict__ W, unsigned short* __restrict__ wt) {
  __shared__ float t[32][33];
  int bx = blockIdx.x;
  int r = bx >> 6;
  int rem = bx & 63;
  int d0 = (rem >> 2) << 5;   // 16 d-tiles of 32
  int c0 = (rem & 3) << 5;    // 4 c-tiles of 32
  int tx = threadIdx.x & 31, ty = threadIdx.x >> 5;  // 32 x 8
  const float* Wr = W + (size_t)r * D_ * C_;
#pragma unroll
  for (int q = 0; q < 4; ++q) {
    int dl = q * 8 + ty;
    t[dl][tx] = Wr[(size_t)(d0 + dl) * C_ + c0 + tx];
  }
  __syncthreads();
  unsigned short* wtr = wt + (size_t)r * C_ * D_;
#pragma unroll
  for (int q = 0; q < 4; ++q) {
    int cl = q * 8 + ty;
    float v = t[tx][cl];                         // transposed read, pad-33 conflict-free
    wtr[(size_t)(c0 + cl) * D_ + d0 + tx] = f2bf(v);
  }
}

// ---------------- prep: (s, -p*s) per (rule, dim) ----------------
__global__ void prep_ps_kernel(const float* __restrict__ proto, const float* __restrict__ var,
                               float* __restrict__ ps) {
  int i = blockIdx.x * 256 + threadIdx.x;          // R*D elements
  float v = fminf(fmaxf(var[i], 1e-4f), 0.1f);
  float s = 1.2011224087864498f / v;
  float2 o; o.x = s; o.y = -proto[i] * s;
  reinterpret_cast<float2*>(ps)[i] = o;
}

// ---------------- antecedent partial: fs_ini accumulation ----------------
__global__ __launch_bounds__(256, 4) void fs_partial_kernel(
    const float* __restrict__ x, const float* __restrict__ ps,
    float* __restrict__ fire) {
  __shared__ float x_s[16 * 68];
  __shared__ __align__(16) float ps_s[64 * 128];   // [rule][dim*2], XOR-swizzled granules
  const int tid = threadIdx.x;
  const int b0 = blockIdx.x * 16;
  const int dq = blockIdx.y;                       // dims dq*64 .. dq*64+63

  {  // stage x tile: 16 rows x 64 dims
    int row = tid >> 4, c4 = tid & 15;
    float4 v = *reinterpret_cast<const float4*>(&x[(size_t)(b0 + row) * D_ + dq * 64 + c4 * 4]);
    *reinterpret_cast<float4*>(&x_s[row * 68 + c4 * 4]) = v;
  }
#pragma unroll
  for (int k = 0; k < 8; ++k) {  // stage ps tile: 64 rules x 32 granules(16B), swizzled
    int g = tid + k * 256;
    int row = g >> 5, gi = g & 31;
    float4 v = *reinterpret_cast<const float4*>(&ps[(size_t)row * (D_ * 2) + dq * 128 + gi * 4]);
    int gs = gi ^ (row & 31);
    *reinterpret_cast<float4*>((char*)ps_s + row * 512 + (gs << 4)) = v;
  }
  __syncthreads();

  const int tr = tid & 63;   // rule = lane
  const int tb = tid >> 6;   // wave -> 4 batch rows
  const int s31 = tr & 31;
  const char* pb = (const char*)ps_s + tr * 512;
  float facc[4] = {0.f, 0.f, 0.f, 0.f};

#pragma unroll
  for (int d4 = 0; d4 < 16; ++d4) {
    float4 psa = *reinterpret_cast<const float4*>(pb + ((((d4 * 2) ^ s31)) << 4));
    float4 psb = *reinterpret_cast<const float4*>(pb + ((((d4 * 2 + 1) ^ s31)) << 4));
#pragma unroll
    for (int i = 0; i < 4; ++i) {
      float4 xv = *reinterpret_cast<const float4*>(&x_s[(tb * 4 + i) * 68 + d4 * 4]);
      float u0 = fmaf(xv.x, psa.x, psa.y);
      float u1 = fmaf(xv.y, psa.z, psa.w);
      float u2 = fmaf(xv.z, psb.x, psb.y);
      float u3 = fmaf(xv.w, psb.z, psb.w);
      facc[i] += exp2f(-(u0 * u0)) + exp2f(-(u1 * u1)) +
                 exp2f(-(u2 * u2)) + exp2f(-(u3 * u3));
    }
  }
#pragma unroll
  for (int i = 0; i < 4; ++i)
    atomicAdd(&fire[(size_t)(b0 + tb * 4 + i) * R_ + tr], facc[i]);
}

// ---------------- softmax over rules, in place on fire buffer ----------------
__global__ void softmax_kernel(float* __restrict__ fire) {
  const int b = blockIdx.x * 4 + (threadIdx.x >> 6);
  const int r = threadIdx.x & 63;
  float v = fire[(size_t)b * R_ + r];
  float m = v;
#pragma unroll
  for (int off = 32; off; off >>= 1) m = fmaxf(m, __shfl_xor(m, off, 64));
  float e = exp2f((v - m) * 1.4426950408889634f);
  float s = e;
#pragma unroll
  for (int off = 32; off; off >>= 1) s += __shfl_xor(s, off, 64);
  fire[(size_t)b * R_ + r] = e / s;
}

// ---------------- fused rule-GEMM + relu + fire-weighted combine ----------------
// Occupancy-first config: BM=64, BN=C=128, BK=32, 4 rules/block.
// 4 waves (2x2), wave tile 32x64. LDS 25KB, VGPR capped 128 -> 4 blocks/CU,
// 16 waves/CU. Simple dbuf drain loop; cross-block TLP hides stalls (m114).
__global__ __launch_bounds__(256, 4) void gemm_kernel(
    const unsigned short* __restrict__ xw, const unsigned short* __restrict__ wt,
    const float* __restrict__ fire, const float* __restrict__ bias,
    float* __restrict__ out) {
  __shared__ __align__(16) unsigned short x_s[2][64 * 32];    // 2 x 4 KB
  __shared__ __align__(16) unsigned short w_s[2][128 * 32];   // 2 x 8 KB
  __shared__ float fire_s[64 * 4];                            // 1 KB
  __shared__ float bias_s[4 * 128];                           // 2 KB

  const int tid = threadIdx.x;       // 0..255
  const int rg = blockIdx.x;         // 0..15 rule group (4 rules); rg%8 pins W slice to XCD
  const int bm = blockIdx.y;         // 0..63 batch block
  const int b0 = bm * 64;

  {
    int row = tid >> 2, g = tid & 3;
    fire_s[tid] = fire[(size_t)(b0 + row) * R_ + rg * 4 + g];
    bias_s[tid] = bias[rg * 4 * C_ + tid];
    bias_s[tid + 256] = bias[rg * 4 * C_ + tid + 256];
  }

  const int wid = tid >> 6, lane = tid & 63;
  const int wm = wid >> 1, wn = wid & 1;           // 2 x 2 wave grid, wave tile 32x64
  const int l16 = lane & 15, lhi = lane >> 4;

  // ds_read byte offsets (XOR-swizzled 16B granules within 64B rows)
  int offA[2], offB[4];
#pragma unroll
  for (int m = 0; m < 2; ++m) {
    int row = wm * 32 + m * 16 + l16;              // 0..63
    offA[m] = row * 64 + ((lhi ^ (row & 3)) << 4);
  }
#pragma unroll
  for (int n = 0; n < 4; ++n) {
    int row = wn * 64 + n * 16 + l16;              // 0..127
    offB[n] = row * 64 + ((lhi ^ (row & 3)) << 4);
  }

  // staging offsets (elements), inverse-swizzled global source
  int a_off, a_dst;
  {
    int ch = tid;                                  // A: 256 chunks of 16B (64 rows x 4)
    int row = ch >> 2, g4 = ch & 3;
    a_off = row * D_ + ((g4 ^ (row & 3)) << 3);
    a_dst = ch * 8;
  }
  int b_off[2], b_dst[2];
#pragma unroll
  for (int q = 0; q < 2; ++q) {                    // B: 512 chunks of 16B (128 rows x 4)
    int ch = q * 256 + tid;
    int row = ch >> 2, g4 = ch & 3;
    b_off[q] = row * D_ + ((g4 ^ (row & 3)) << 3);
    b_dst[q] = ch * 8;
  }

  const unsigned short* xsrc = xw + (size_t)b0 * D_;
  const unsigned short* wbase = wt + (size_t)(rg * 4) * C_ * D_;

  auto stageA = [&](unsigned short* lds, int kc) {
    __builtin_amdgcn_global_load_lds(
        (const __attribute__((address_space(1))) void*)(xsrc + a_off + kc),
        (__attribute__((address_space(3))) void*)(lds + a_dst), 16, 0, 0);
  };
  auto stageB = [&](unsigned short* lds, const unsigned short* src, int kc) {
#pragma unroll
    for (int q = 0; q < 2; ++q)
      __builtin_amdgcn_global_load_lds(
          (const __attribute__((address_space(1))) void*)(src + b_off[q] + kc),
          (__attribute__((address_space(3))) void*)(lds + b_dst[q]), 16, 0, 0);
  };

  float tot[2][4][4];
#pragma unroll
  for (int m = 0; m < 2; ++m)
#pragma unroll
    for (int n = 0; n < 4; ++n)
#pragma unroll
      for (int j = 0; j < 4; ++j) tot[m][n][j] = 0.f;

  f32x4 acc[2][4];

  stageA(x_s[0], 0);
  stageB(w_s[0], wbase, 0);
  __syncthreads();

  int cur = 0;
  for (int s = 0; s < 64; ++s) {                   // s = rule*16 + k-chunk
    const int g = s >> 4, kk = s & 15;
    if (kk == 0) {
#pragma unroll
      for (int m = 0; m < 2; ++m)
#pragma unroll
        for (int n = 0; n < 4; ++n)
          acc[m][n] = f32x4{0.f, 0.f, 0.f, 0.f};
    }
    if (s + 1 < 64) {                              // prefetch next tile into other buf
      const int s1 = s + 1;
      stageA(x_s[cur ^ 1], (s1 & 15) * 32);
      stageB(w_s[cur ^ 1], wbase + (size_t)(s1 >> 4) * C_ * D_, (s1 & 15) * 32);
    }
    const char* xb = (const char*)x_s[cur];
    const char* wb = (const char*)w_s[cur];
    bf16x8 av[2], bv[4];
#pragma unroll
    for (int m = 0; m < 2; ++m)
      av[m] = *reinterpret_cast<const bf16x8*>(xb + offA[m]);
#pragma unroll
    for (int n = 0; n < 4; ++n)
      bv[n] = *reinterpret_cast<const bf16x8*>(wb + offB[n]);
#pragma unroll
    for (int m = 0; m < 2; ++m)
#pragma unroll
      for (int n = 0; n < 4; ++n)
        acc[m][n] = __builtin_amdgcn_mfma_f32_16x16x32_bf16(av[m], bv[n], acc[m][n], 0, 0, 0);
    if (kk == 15) {  // rule g finished: relu(+bias) * fire, accumulate
#pragma unroll
      for (int m = 0; m < 2; ++m)
#pragma unroll
        for (int n = 0; n < 4; ++n) {
          int col = wn * 64 + n * 16 + l16;
          float bi = bias_s[g * 128 + col];
#pragma unroll
          for (int j = 0; j < 4; ++j) {
            int rowl = wm * 32 + m * 16 + lhi * 4 + j;
            float v = acc[m][n][j] + bi;
            v = fmaxf(v, 0.f);
            tot[m][n][j] += v * fire_s[rowl * 4 + g];
          }
        }
    }
    __syncthreads();   // drains vmcnt/lgkm; cross-block waves hide this
    cur ^= 1;
  }

#pragma unroll
  for (int m = 0; m < 2; ++m)
#pragma unroll
    for (int n = 0; n < 4; ++n) {
      int col = wn * 64 + n * 16 + l16;
#pragma unroll
      for (int j = 0; j < 4; ++j) {
        int rowl = wm * 32 + m * 16 + lhi * 4 + j;
        atomicAdd(&out[(size_t)(b0 + rowl) * C_ + col], tot[m][n][j]);
      }
    }
}

extern "C" void kernel_launch(void* const* d_in, const int* in_sizes, int n_in,
                              void* d_out, int out_size, void* d_ws, size_t ws_size,
                              hipStream_t stream) {
  const float* x     = (const float*)d_in[0];
  const float* proto = (const float*)d_in[1];
  const float* var   = (const float*)d_in[2];
  const float* W     = (const float*)d_in[3];
  const float* bias  = (const float*)d_in[4];
  float* out  = (float*)d_out;
  float* fire = out + (size_t)B_ * C_;   // second output region (also fs_ini accumulator)

  const size_t WS_X  = (size_t)B_ * D_ * sizeof(unsigned short);       // 4 MiB
  const size_t WS_WT = (size_t)R_ * C_ * D_ * sizeof(unsigned short);  // 8 MiB
  const size_t WS_PS = (size_t)R_ * D_ * 2 * sizeof(float);            // 256 KiB
  if (ws_size < WS_X + WS_WT + WS_PS) return;  // insufficient scratch -> visible failure

  unsigned short* xw  = (unsigned short*)d_ws;
  unsigned short* wtp = (unsigned short*)((char*)d_ws + WS_X);
  float*          ps  = (float*)((char*)d_ws + WS_X + WS_WT);

  // zero BOTH output regions: out accumulates gemm atomics, fire accumulates fs partials
  hipMemsetAsync(d_out, 0, (size_t)out_size * sizeof(float), stream);
  prep_x_kernel<<<dim3((B_ * D_ / 4) / 256), dim3(256), 0, stream>>>(x, xw);
  prep_w_kernel<<<dim3(R_ * 64), dim3(256), 0, stream>>>(W, wtp);
  prep_ps_kernel<<<dim3(R_ * D_ / 256), dim3(256), 0, stream>>>(proto, var, ps);
  fs_partial_kernel<<<dim3(B_ / 16, 8), dim3(256), 0, stream>>>(x, ps, fire);
  softmax_kernel<<<dim3(B_ / 4), dim3(256), 0, stream>>>(fire);
  gemm_kernel<<<dim3(16, 64), dim3(256), 0, stream>>>(xw, wtp, fire, bias, out);
}

// Round 7
// 128.738 us; speedup vs baseline: 1.0041x; 1.0041x over previous
//
#include <hip/hip_runtime.h>
#include <hip/hip_bf16.h>
#include <cmath>

#define R_ 64
#define B_ 4096
#define D_ 512
#define C_ 128

typedef __attribute__((ext_vector_type(8))) short bf16x8;
typedef __attribute__((ext_vector_type(4))) float f32x4;

__device__ __forceinline__ unsigned short f2bf(float f) {
  union { float f; unsigned u; } x; x.f = f;
  unsigned r = (x.u + 0x7FFFu + ((x.u >> 16) & 1u)) >> 16;
  return (unsigned short)r;
}

// ---------------- prep: x f32 -> bf16 ----------------
__global__ void prep_x_kernel(const float* __restrict__ x, unsigned short* __restrict__ xw) {
  int i = blockIdx.x * 256 + threadIdx.x;          // float4 index, exact count
  float4 v = reinterpret_cast<const float4*>(x)[i];
  ushort4 o;
  o.x = f2bf(v.x); o.y = f2bf(v.y); o.z = f2bf(v.z); o.w = f2bf(v.w);
  reinterpret_cast<ushort4*>(xw)[i] = o;
}

// ---------------- prep: W[r][d][c] f32 -> W^T[r][c][d] bf16 ----------------
__global__ void prep_w_kernel(const float* __restrict__ W, unsigned short* __restrict__ wt) {
  __shared__ float t[32][33];
  int bx = blockIdx.x;
  int r = bx >> 6;
  int rem = bx & 63;
  int d0 = (rem >> 2) << 5;   // 16 d-tiles of 32
  int c0 = (rem & 3) << 5;    // 4 c-tiles of 32
  int tx = threadIdx.x & 31, ty = threadIdx.x >> 5;  // 32 x 8
  const float* Wr = W + (size_t)r * D_ * C_;
#pragma unroll
  for (int q = 0; q < 4; ++q) {
    int dl = q * 8 + ty;
    t[dl][tx] = Wr[(size_t)(d0 + dl) * C_ + c0 + tx];
  }
  __syncthreads();
  unsigned short* wtr = wt + (size_t)r * C_ * D_;
#pragma unroll
  for (int q = 0; q < 4; ++q) {
    int cl = q * 8 + ty;
    float v = t[tx][cl];                         // transposed read, pad-33 conflict-free
    wtr[(size_t)(c0 + cl) * D_ + d0 + tx] = f2bf(v);
  }
}

// ---------------- prep: (s, -p*s) per (rule, dim) ----------------
__global__ void prep_ps_kernel(const float* __restrict__ proto, const float* __restrict__ var,
                               float* __restrict__ ps) {
  int i = blockIdx.x * 256 + threadIdx.x;          // R*D elements
  float v = fminf(fmaxf(var[i], 1e-4f), 0.1f);
  float s = 1.2011224087864498f / v;
  float2 o; o.x = s; o.y = -proto[i] * s;
  reinterpret_cast<float2*>(ps)[i] = o;
}

// ---------------- antecedent partial: fs_ini accumulation ----------------
__global__ __launch_bounds__(256, 4) void fs_partial_kernel(
    const float* __restrict__ x, const float* __restrict__ ps,
    float* __restrict__ fire) {
  __shared__ float x_s[16 * 68];
  __shared__ __align__(16) float ps_s[64 * 128];   // [rule][dim*2], XOR-swizzled granules
  const int tid = threadIdx.x;
  const int b0 = blockIdx.x * 16;
  const int dq = blockIdx.y;                       // dims dq*64 .. dq*64+63

  {  // stage x tile: 16 rows x 64 dims
    int row = tid >> 4, c4 = tid & 15;
    float4 v = *reinterpret_cast<const float4*>(&x[(size_t)(b0 + row) * D_ + dq * 64 + c4 * 4]);
    *reinterpret_cast<float4*>(&x_s[row * 68 + c4 * 4]) = v;
  }
#pragma unroll
  for (int k = 0; k < 8; ++k) {  // stage ps tile: 64 rules x 32 granules(16B), swizzled
    int g = tid + k * 256;
    int row = g >> 5, gi = g & 31;
    float4 v = *reinterpret_cast<const float4*>(&ps[(size_t)row * (D_ * 2) + dq * 128 + gi * 4]);
    int gs = gi ^ (row & 31);
    *reinterpret_cast<float4*>((char*)ps_s + row * 512 + (gs << 4)) = v;
  }
  __syncthreads();

  const int tr = tid & 63;   // rule = lane
  const int tb = tid >> 6;   // wave -> 4 batch rows
  const int s31 = tr & 31;
  const char* pb = (const char*)ps_s + tr * 512;
  float facc[4] = {0.f, 0.f, 0.f, 0.f};

#pragma unroll
  for (int d4 = 0; d4 < 16; ++d4) {
    float4 psa = *reinterpret_cast<const float4*>(pb + ((((d4 * 2) ^ s31)) << 4));
    float4 psb = *reinterpret_cast<const float4*>(pb + ((((d4 * 2 + 1) ^ s31)) << 4));
#pragma unroll
    for (int i = 0; i < 4; ++i) {
      float4 xv = *reinterpret_cast<const float4*>(&x_s[(tb * 4 + i) * 68 + d4 * 4]);
      float u0 = fmaf(xv.x, psa.x, psa.y);
      float u1 = fmaf(xv.y, psa.z, psa.w);
      float u2 = fmaf(xv.z, psb.x, psb.y);
      float u3 = fmaf(xv.w, psb.z, psb.w);
      facc[i] += exp2f(-(u0 * u0)) + exp2f(-(u1 * u1)) +
                 exp2f(-(u2 * u2)) + exp2f(-(u3 * u3));
    }
  }
#pragma unroll
  for (int i = 0; i < 4; ++i)
    atomicAdd(&fire[(size_t)(b0 + tb * 4 + i) * R_ + tr], facc[i]);
}

// ---------------- softmax over rules, in place on fire buffer ----------------
__global__ void softmax_kernel(float* __restrict__ fire) {
  const int b = blockIdx.x * 4 + (threadIdx.x >> 6);
  const int r = threadIdx.x & 63;
  float v = fire[(size_t)b * R_ + r];
  float m = v;
#pragma unroll
  for (int off = 32; off; off >>= 1) m = fmaxf(m, __shfl_xor(m, off, 64));
  float e = exp2f((v - m) * 1.4426950408889634f);
  float s = e;
#pragma unroll
  for (int off = 32; off; off >>= 1) s += __shfl_xor(s, off, 64);
  fire[(size_t)b * R_ + r] = e / s;
}

// ---------------- fused rule-GEMM + relu + fire-weighted combine ----------------
// Occupancy-first config: BM=64, BN=C=128, BK=32, 4 rules/block.
// 4 waves (2x2), wave tile 32x64. LDS 25KB, VGPR capped 128 -> 4 blocks/CU,
// 16 waves/CU. Simple dbuf drain loop; cross-block TLP hides stalls (m114).
__global__ __launch_bounds__(256, 4) void gemm_kernel(
    const unsigned short* __restrict__ xw, const unsigned short* __restrict__ wt,
    const float* __restrict__ fire, const float* __restrict__ bias,
    float* __restrict__ out) {
  __shared__ __align__(16) unsigned short x_s[2][64 * 32];    // 2 x 4 KB
  __shared__ __align__(16) unsigned short w_s[2][128 * 32];   // 2 x 8 KB
  __shared__ float fire_s[64 * 4];                            // 1 KB
  __shared__ float bias_s[4 * 128];                           // 2 KB

  const int tid = threadIdx.x;       // 0..255
  const int rg = blockIdx.x;         // 0..15 rule group (4 rules); rg%8 pins W slice to XCD
  const int bm = blockIdx.y;         // 0..63 batch block
  const int b0 = bm * 64;

  {
    int row = tid >> 2, g = tid & 3;
    fire_s[tid] = fire[(size_t)(b0 + row) * R_ + rg * 4 + g];
    bias_s[tid] = bias[rg * 4 * C_ + tid];
    bias_s[tid + 256] = bias[rg * 4 * C_ + tid + 256];
  }

  const int wid = tid >> 6, lane = tid & 63;
  const int wm = wid >> 1, wn = wid & 1;           // 2 x 2 wave grid, wave tile 32x64
  const int l16 = lane & 15, lhi = lane >> 4;

  // ds_read byte offsets (XOR-swizzled 16B granules within 64B rows)
  int offA[2], offB[4];
#pragma unroll
  for (int m = 0; m < 2; ++m) {
    int row = wm * 32 + m * 16 + l16;              // 0..63
    offA[m] = row * 64 + ((lhi ^ (row & 3)) << 4);
  }
#pragma unroll
  for (int n = 0; n < 4; ++n) {
    int row = wn * 64 + n * 16 + l16;              // 0..127
    offB[n] = row * 64 + ((lhi ^ (row & 3)) << 4);
  }

  // staging offsets (elements), inverse-swizzled global source
  int a_off, a_dst;
  {
    int ch = tid;                                  // A: 256 chunks of 16B (64 rows x 4)
    int row = ch >> 2, g4 = ch & 3;
    a_off = row * D_ + ((g4 ^ (row & 3)) << 3);
    a_dst = ch * 8;
  }
  int b_off[2], b_dst[2];
#pragma unroll
  for (int q = 0; q < 2; ++q) {                    // B: 512 chunks of 16B (128 rows x 4)
    int ch = q * 256 + tid;
    int row = ch >> 2, g4 = ch & 3;
    b_off[q] = row * D_ + ((g4 ^ (row & 3)) << 3);
    b_dst[q] = ch * 8;
  }

  const unsigned short* xsrc = xw + (size_t)b0 * D_;
  const unsigned short* wbase = wt + (size_t)(rg * 4) * C_ * D_;

  auto stageA = [&](unsigned short* lds, int kc) {
    __builtin_amdgcn_global_load_lds(
        (const __attribute__((address_space(1))) void*)(xsrc + a_off + kc),
        (__attribute__((address_space(3))) void*)(lds + a_dst), 16, 0, 0);
  };
  auto stageB = [&](unsigned short* lds, const unsigned short* src, int kc) {
#pragma unroll
    for (int q = 0; q < 2; ++q)
      __builtin_amdgcn_global_load_lds(
          (const __attribute__((address_space(1))) void*)(src + b_off[q] + kc),
          (__attribute__((address_space(3))) void*)(lds + b_dst[q]), 16, 0, 0);
  };

  float tot[2][4][4];
#pragma unroll
  for (int m = 0; m < 2; ++m)
#pragma unroll
    for (int n = 0; n < 4; ++n)
#pragma unroll
      for (int j = 0; j < 4; ++j) tot[m][n][j] = 0.f;

  f32x4 acc[2][4];

  stageA(x_s[0], 0);
  stageB(w_s[0], wbase, 0);
  __syncthreads();

  int cur = 0;
  for (int s = 0; s < 64; ++s) {                   // s = rule*16 + k-chunk
    const int g = s >> 4, kk = s & 15;
    if (kk == 0) {
#pragma unroll
      for (int m = 0; m < 2; ++m)
#pragma unroll
        for (int n = 0; n < 4; ++n)
          acc[m][n] = f32x4{0.f, 0.f, 0.f, 0.f};
    }
    if (s + 1 < 64) {                              // prefetch next tile into other buf
      const int s1 = s + 1;
      stageA(x_s[cur ^ 1], (s1 & 15) * 32);
      stageB(w_s[cur ^ 1], wbase + (size_t)(s1 >> 4) * C_ * D_, (s1 & 15) * 32);
    }
    const char* xb = (const char*)x_s[cur];
    const char* wb = (const char*)w_s[cur];
    bf16x8 av[2], bv[4];
#pragma unroll
    for (int m = 0; m < 2; ++m)
      av[m] = *reinterpret_cast<const bf16x8*>(xb + offA[m]);
#pragma unroll
    for (int n = 0; n < 4; ++n)
      bv[n] = *reinterpret_cast<const bf16x8*>(wb + offB[n]);
#pragma unroll
    for (int m = 0; m < 2; ++m)
#pragma unroll
      for (int n = 0; n < 4; ++n)
        acc[m][n] = __builtin_amdgcn_mfma_f32_16x16x32_bf16(av[m], bv[n], acc[m][n], 0, 0, 0);
    if (kk == 15) {  // rule g finished: relu(+bias) * fire, accumulate
#pragma unroll
      for (int m = 0; m < 2; ++m)
#pragma unroll
        for (int n = 0; n < 4; ++n) {
          int col = wn * 64 + n * 16 + l16;
          float bi = bias_s[g * 128 + col];
#pragma unroll
          for (int j = 0; j < 4; ++j) {
            int rowl = wm * 32 + m * 16 + lhi * 4 + j;
            float v = acc[m][n][j] + bi;
            v = fmaxf(v, 0.f);
            tot[m][n][j] += v * fire_s[rowl * 4 + g];
          }
        }
    }
    __syncthreads();   // drains vmcnt/lgkm; cross-block waves hide this
    cur ^= 1;
  }

#pragma unroll
  for (int m = 0; m < 2; ++m)
#pragma unroll
    for (int n = 0; n < 4; ++n) {
      int col = wn * 64 + n * 16 + l16;
#pragma unroll
      for (int j = 0; j < 4; ++j) {
        int rowl = wm * 32 + m * 16 + lhi * 4 + j;
        atomicAdd(&out[(size_t)(b0 + rowl) * C_ + col], tot[m][n][j]);
      }
    }
}

extern "C" void kernel_launch(void* const* d_in, const int* in_sizes, int n_in,
                              void* d_out, int out_size, void* d_ws, size_t ws_size,
                              hipStream_t stream) {
  const float* x     = (const float*)d_in[0];
  const float* proto = (const float*)d_in[1];
  const float* var   = (const float*)d_in[2];
  const float* W     = (const float*)d_in[3];
  const float* bias  = (const float*)d_in[4];
  float* out  = (float*)d_out;
  float* fire = out + (size_t)B_ * C_;   // second output region (also fs_ini accumulator)

  const size_t WS_X  = (size_t)B_ * D_ * sizeof(unsigned short);       // 4 MiB
  const size_t WS_WT = (size_t)R_ * C_ * D_ * sizeof(unsigned short);  // 8 MiB
  const size_t WS_PS = (size_t)R_ * D_ * 2 * sizeof(float);            // 256 KiB
  if (ws_size < WS_X + WS_WT + WS_PS) return;  // insufficient scratch -> visible failure

  unsigned short* xw  = (unsigned short*)d_ws;
  unsigned short* wtp = (unsigned short*)((char*)d_ws + WS_X);
  float*          ps  = (float*)((char*)d_ws + WS_X + WS_WT);

  // zero BOTH output regions: out accumulates gemm atomics, fire accumulates fs partials
  hipMemsetAsync(d_out, 0, (size_t)out_size * sizeof(float), stream);
  prep_x_kernel<<<dim3((B_ * D_ / 4) / 256), dim3(256), 0, stream>>>(x, xw);
  prep_w_kernel<<<dim3(R_ * 64), dim3(256), 0, stream>>>(W, wtp);
  prep_ps_kernel<<<dim3(R_ * D_ / 256), dim3(256), 0, stream>>>(proto, var, ps);
  fs_partial_kernel<<<dim3(B_ / 16, 8), dim3(256), 0, stream>>>(x, ps, fire);
  softmax_kernel<<<dim3(B_ / 4), dim3(256), 0, stream>>>(fire);
  gemm_kernel<<<dim3(16, 64), dim3(256), 0, stream>>>(xw, wtp, fire, bias, out);
}